// Round 8
// baseline (116.282 us; speedup 1.0000x reference)
//
#include <hip/hip_runtime.h>

// ---------------- workspace layout (bytes) ----------------
#define WS_H      192        // i32[10] class counts (contiguous, written by k_rows)
#define WS_PART   2048       // f32[1764*2] per-block partials
#define WS_SSQ    65536      // f32[40960]  sumsq, class-sorted slots (160 KB)
#define WS_PROJT  262144     // f32[10][40960] proj*invwn[c], class-sorted (1.6 MB)
#define WS_SPRED  2097152    // bf16[40960][128] class-sorted rows (10 MB)

#define NCLS 10
#define NROW 4096
#define DDIM 128
#define SLOTS 40960          // 10 * 4096
#define MAXT 42
#define GRID_MAIN (MAXT * MAXT)

typedef __attribute__((ext_vector_type(8))) short short8;
typedef __attribute__((ext_vector_type(4))) float f32x4;

__device__ __forceinline__ unsigned short f2bf(float x) {
  unsigned int u = __float_as_uint(x);
  u += 0x7FFFu + ((u >> 16) & 1u);   // round-nearest-even
  return (unsigned short)(u >> 16);
}
__device__ __forceinline__ float bf2f(unsigned short b) {
  return __uint_as_float(((unsigned int)b) << 16);
}

// ---------------- K1: bf16 convert + sumsq + proj, written CLASS-SORTED ----
// 256 blocks x 256 thr; 16 rows/block, 16 threads/row; W in LDS.
// Slots are DETERMINISTIC: rank-within-class via register prefix-count over
// tgt[0..blockStart). NO global atomics anywhere; last block writes h[10].
__global__ void __launch_bounds__(256)
k_rows(const float* __restrict__ pred, const float* __restrict__ W,
       const int* __restrict__ tgt, char* __restrict__ ws) {
  __shared__ float Wl[NCLS * DDIM];
  __shared__ float invwn_s[NCLS];
  __shared__ int wred[4][NCLS];
  __shared__ int slot_s[16];
  int t = threadIdx.x;
  for (int s = t; s < NCLS * DDIM; s += 256) Wl[s] = W[s];

  // ---- prefix counts over [0, r0): each thread a strided slice ----
  const int r0 = blockIdx.x * 16;
  int cnt[NCLS];
#pragma unroll
  for (int c = 0; c < NCLS; c++) cnt[c] = 0;
  for (int j = t; j < r0; j += 256) {
    int v = tgt[j];
#pragma unroll
    for (int c = 0; c < NCLS; c++) cnt[c] += (v == c) ? 1 : 0;
  }
#pragma unroll
  for (int m = 1; m <= 32; m <<= 1) {
#pragma unroll
    for (int c = 0; c < NCLS; c++) cnt[c] += __shfl_xor(cnt[c], m, 64);
  }
  const int lane = t & 63, w = t >> 6;
  if (lane == 0) {
#pragma unroll
    for (int c = 0; c < NCLS; c++) wred[w][c] = cnt[c];
  }
  __syncthreads();                     // wred + Wl ready

  if (t == 0) {
    int base[NCLS];
#pragma unroll
    for (int c = 0; c < NCLS; c++)
      base[c] = wred[0][c] + wred[1][c] + wred[2][c] + wred[3][c];
    for (int i = 0; i < 16; i++) {     // local ranks, in row order
      int c = tgt[r0 + i];
      slot_s[i] = c * NROW + base[c];
      base[c]++;
    }
    if (blockIdx.x == gridDim.x - 1) { // base == full histogram here
#pragma unroll
      for (int c = 0; c < NCLS; c++) ((int*)(ws + WS_H))[c] = base[c];
    }
  }
  if (t >= 64 && t < 224) {            // invwn: 16 lanes/class, into LDS
    int i = t - 64;
    int c = i >> 4, ln = i & 15;
    float sw = 0.f;
#pragma unroll
    for (int k = 0; k < 8; k++) { float ww = Wl[c * DDIM + ln * 8 + k]; sw = fmaf(ww, ww, sw); }
    sw += __shfl_xor(sw, 1, 64);
    sw += __shfl_xor(sw, 2, 64);
    sw += __shfl_xor(sw, 4, 64);
    sw += __shfl_xor(sw, 8, 64);
    if (ln == 0) invwn_s[c] = 1.0f / fmaxf(sqrtf(sw), 1e-8f);
  }
  __syncthreads();                     // slot_s + invwn_s ready

  // ---- heavy row compute: 16 threads/row, 8 dims each ----
  int row  = r0 + (t >> 4);
  int part = t & 15;
  int slot = slot_s[t >> 4];
  const float4* p4 = (const float4*)(pred + row * DDIM + part * 8);
  unsigned short* pb = ((unsigned short*)(ws + WS_SPRED)) + slot * DDIM + part * 8;

  float4 v[2];
  float ss = 0.f;
#pragma unroll
  for (int ch = 0; ch < 2; ch++) {
    v[ch] = p4[ch];
    unsigned short b0 = f2bf(v[ch].x), b1 = f2bf(v[ch].y),
                   b2 = f2bf(v[ch].z), b3 = f2bf(v[ch].w);
    float r0f = bf2f(b0), r1f = bf2f(b1), r2f = bf2f(b2), r3f = bf2f(b3);
    ss = fmaf(r0f, r0f, ss); ss = fmaf(r1f, r1f, ss);
    ss = fmaf(r2f, r2f, ss); ss = fmaf(r3f, r3f, ss);
    ushort4 u; u.x = b0; u.y = b1; u.z = b2; u.w = b3;
    *((ushort4*)(pb + ch * 4)) = u;
  }
  float acc[NCLS];
#pragma unroll
  for (int c = 0; c < NCLS; c++) acc[c] = 0.f;
#pragma unroll
  for (int c = 0; c < NCLS; c++) {
#pragma unroll
    for (int ch = 0; ch < 2; ch++) {
      float4 ww = *(const float4*)&Wl[c * DDIM + part * 8 + ch * 4];
      acc[c] = fmaf(v[ch].x, ww.x, acc[c]);
      acc[c] = fmaf(v[ch].y, ww.y, acc[c]);
      acc[c] = fmaf(v[ch].z, ww.z, acc[c]);
      acc[c] = fmaf(v[ch].w, ww.w, acc[c]);
    }
  }
#pragma unroll
  for (int m = 1; m <= 8; m <<= 1) {
    ss += __shfl_xor(ss, m, 64);
#pragma unroll
    for (int c = 0; c < NCLS; c++) acc[c] += __shfl_xor(acc[c], m, 64);
  }
  if (part == 0) {
    ((float*)(ws + WS_SSQ))[slot] = ss;
    float* projT = (float*)(ws + WS_PROJT);
#pragma unroll
    for (int c = 0; c < NCLS; c++) projT[c * SLOTS + slot] = acc[c] * invwn_s[c];
  }
}

// ---------------- K2: class-tile x class-tile MFMA + fused epilogue ----------
// grid 42*42, 256 thr (4 waves). All data class-sorted contiguous. B-frags
// streamed DIRECTLY from L2 with depth-2 register double-buffer (no LDS tile,
// no staging barrier). Only barrier: the 4-wave final reduce. No atomics.
__global__ void __launch_bounds__(256)
k_main(char* __restrict__ ws) {
  const int t = threadIdx.x;
  const int* hp = (const int*)(ws + WS_H);
  int h[NCLS];
#pragma unroll
  for (int c = 0; c < NCLS; c++) h[c] = hp[c];

  int at = blockIdx.x / MAXT, bt = blockIdx.x % MAXT;
  int acc = 0, clsA = 0, ka = 0, clsB = 0, kb = 0;
#pragma unroll
  for (int c = 0; c < NCLS; c++) {
    int tc = (h[c] + 127) >> 7;
    if (at >= acc && at < acc + tc) { clsA = c; ka = at - acc; }
    if (bt >= acc && bt < acc + tc) { clsB = c; kb = bt - acc; }
    acc += tc;
  }
  const int ntiles = acc;
  const bool active = (at < ntiles) && (bt < ntiles) && (clsA != clsB);

  __shared__ float red_s[4][2];
  float p1 = 0.f, p2 = 0.f;

  if (active) {
    const int abase = clsA * NROW + ka * 128;       // sorted slot base, A tile
    const int bbase = clsB * NROW + kb * 128;       // sorted slot base, B tile
    const int avcnt = min(128, h[clsA] - ka * 128);
    const int bvcnt = min(128, h[clsB] - kb * 128);
    const float wg = (1.0f / (float)h[clsA]) * (1.0f / (float)h[clsB]);
    const float INF = __builtin_inff();

    const float* ssq  = (const float*)(ws + WS_SSQ);
    const float* prjA = (const float*)(ws + WS_PROJT) + clsA * SLOTS;
    const unsigned short* spred = (const unsigned short*)(ws + WS_SPRED);

    const int lane = t & 63, w = t >> 6;
    const int l16 = lane & 15, quad = lane >> 4;

    // ---- b-side per-lane scalars (epilogue B-index == l16) ----
    float sqbR[8], pnbR[8];
#pragma unroll
    for (int s = 0; s < 8; s++) {
      int bi = s * 16 + l16;
      bool valid = bi < bvcnt;
      sqbR[s] = valid ? ssq[bbase + bi] + 1e-16f : INF;    // pad: M -> 0
      pnbR[s] = valid ? prjA[bbase + bi] : 0.0f;
    }

    // ---- a-side: frags (contiguous rows) + C-layout scalar f32x4 loads ----
    short8 afrag[2][4];
    f32x4 sqa4[2], pa4[2];
#pragma unroll
    for (int fi = 0; fi < 2; fi++) {
      const unsigned short* ap = spred + (abase + w * 32 + fi * 16 + l16) * DDIM + quad * 8;
#pragma unroll
      for (int kk = 0; kk < 4; kk++) afrag[fi][kk] = *(const short8*)(ap + kk * 32);
      int m0 = w * 32 + fi * 16 + quad * 4;                // C-layout row = quad*4+r
      sqa4[fi] = *(const f32x4*)(ssq + abase + m0);
      pa4[fi]  = *(const f32x4*)(prjA + abase + m0);
#pragma unroll
      for (int r = 0; r < 4; r++)
        if (m0 + r >= avcnt) sqa4[fi][r] = INF;            // pad: M -> 0
    }

    // ---- main loop: direct-from-L2 B-frag depth-2 stream + MFMA + epilogue ----
    const unsigned short* bb0 = spred + (size_t)(bbase + l16) * DDIM + quad * 8;
    short8 bcur[4], bnxt[4];
#pragma unroll
    for (int kk = 0; kk < 4; kk++) bcur[kk] = *(const short8*)(bb0 + kk * 32);

    float S1 = 0.f, S2 = 0.f;
#pragma unroll
    for (int s = 0; s < 8; s++) {
      if (s < 7) {
        const unsigned short* bp = bb0 + (size_t)(s + 1) * 16 * DDIM;
#pragma unroll
        for (int kk = 0; kk < 4; kk++) bnxt[kk] = *(const short8*)(bp + kk * 32);
      }
      float sqb = sqbR[s], pnb = pnbR[s];
#pragma unroll
      for (int fi = 0; fi < 2; fi++) {
        f32x4 g = {0.f, 0.f, 0.f, 0.f};
#pragma unroll
        for (int kk = 0; kk < 4; kk++)
          g = __builtin_amdgcn_mfma_f32_16x16x32_bf16(afrag[fi][kk], bcur[kk], g, 0, 0, 0);
#pragma unroll
        for (int r = 0; r < 4; r++) {
          float d2 = fmaf(-2.0f, g[r], sqa4[fi][r] + sqb);   // pads: inf -> rin 0
          float rin = rsqrtf(d2);                            // 1/dn (maxes are no-ops)
          float M = (pa4[fi][r] - pnb) * rin;
          S1 += M;
          S2 = fmaf(M, M, S2);
        }
      }
#pragma unroll
      for (int kk = 0; kk < 4; kk++) bcur[kk] = bnxt[kk];
    }

#pragma unroll
    for (int off = 32; off > 0; off >>= 1) {
      S1 += __shfl_xor(S1, off, 64);
      S2 += __shfl_xor(S2, off, 64);
    }
    if (lane == 0) { red_s[w][0] = S1; red_s[w][1] = S2; }
    __syncthreads();
    if (t == 0) {
      p1 = wg * ((red_s[0][0] + red_s[1][0]) + (red_s[2][0] + red_s[3][0]));
      p2 = wg * ((red_s[0][1] + red_s[1][1]) + (red_s[2][1] + red_s[3][1]));
    }
  }

  if (t == 0) {                        // unique-slot partial (plain store)
    float* part = (float*)(ws + WS_PART);
    part[blockIdx.x * 2]     = p1;
    part[blockIdx.x * 2 + 1] = p2;
  }
}

// ---------------- K3: reduce partials per class, emit outputs ----------
__global__ void __launch_bounds__(256)
k_final(const char* __restrict__ ws, float* __restrict__ out) {
  __shared__ float Sred[2 * NCLS];
  __shared__ int tcls_s[MAXT];
  __shared__ int h_s[NCLS];
  int t = threadIdx.x;
  if (t < 2 * NCLS) Sred[t] = 0.f;
  if (t < NCLS) h_s[t] = ((const int*)(ws + WS_H))[t];
  __syncthreads();
  if (t == 0) {
    int nb = 0;
    for (int c = 0; c < NCLS; c++) {
      int tc = (h_s[c] + 127) >> 7;
      for (int i = 0; i < tc && nb + i < MAXT; i++) tcls_s[nb + i] = c;
      nb += tc;
    }
    for (int i = nb; i < MAXT; i++) tcls_s[i] = 0;   // inactive rows wrote zeros
  }
  __syncthreads();
  const float* part = (const float*)(ws + WS_PART);
  for (int i = t; i < GRID_MAIN; i += 256) {
    int c = tcls_s[i / MAXT];
    float v1 = part[i * 2], v2 = part[i * 2 + 1];
    if (v1 != 0.f || v2 != 0.f) {
      atomicAdd(&Sred[c], v1);
      atomicAdd(&Sred[NCLS + c], v2);
    }
  }
  __syncthreads();
  if (t == 0) {
    float exist = 0.f;
    for (int c = 0; c < NCLS; c++) if (h_s[c] > 0) exist += 1.f;
    float em1 = exist - 1.0f;          // S0 per class == exist-1 (exact)
    float l1 = 0.f, l2 = 0.f;
    for (int c = 0; c < NCLS; c++) {
      if (h_s[c] <= 0) continue;
      float s1 = Sred[c], s2 = Sred[NCLS + c];
      l1 += (em1 - 2.f * s1 + s2) / em1;
      float mm = s1 / em1;
      float mv = s2 / em1 - mm * mm;   // (S2 - 2*mm*S1 + mm^2*S0)/em1, S0=em1
      l2 += fabsf(mv / mm);
    }
    out[0] = l1 / exist;
    out[1] = l2 / exist;
  }
}

extern "C" void kernel_launch(void* const* d_in, const int* in_sizes, int n_in,
                              void* d_out, int out_size, void* d_ws, size_t ws_size,
                              hipStream_t stream) {
  const float* pred = (const float*)d_in[0];
  const int*   tgt  = (const int*)d_in[1];
  const float* W    = (const float*)d_in[2];
  float* out = (float*)d_out;
  char*  ws  = (char*)d_ws;

  k_rows<<<NROW / 16, 256, 0, stream>>>(pred, W, tgt, ws);
  k_main<<<GRID_MAIN, 256, 0, stream>>>(ws);
  k_final<<<1, 256, 0, stream>>>(ws, out);
}

// Round 9
// 93.409 us; speedup vs baseline: 1.2449x; 1.2449x over previous
//
#include <hip/hip_runtime.h>

// ---------------- workspace layout (bytes) ----------------
#define WS_GCUR   192        // i32[10], stride 64B (atomic cursors == class counts)
#define WS_INVWN  896        // f32[10] (not read by k_main; folded in k_rows)
#define WS_PART   2048       // f32[676*2] per-block partials
#define WS_SSQ    65536      // f32[40960]  sumsq, class-sorted slots (160 KB)
#define WS_PROJT  262144     // f32[10][40960] proj*invwn[c], class-sorted (1.6 MB)
#define WS_SPRED  2097152    // bf16[40960][128] class-sorted rows (10 MB)

#define NCLS 10
#define NROW 4096
#define DDIM 128
#define SLOTS 40960          // 10 * 4096
#define TSZ 256              // tile rows
#define MAXT2 26             // max total 256-row class tiles: 16 + 10
#define GRID2 (MAXT2 * MAXT2)

typedef __attribute__((ext_vector_type(8))) short short8;
typedef __attribute__((ext_vector_type(4))) float f32x4;

#define AS3(p) ((__attribute__((address_space(3))) void*)(p))
#define AS1(p) ((const __attribute__((address_space(1))) void*)(p))

__device__ __forceinline__ unsigned short f2bf(float x) {
  unsigned int u = __float_as_uint(x);
  u += 0x7FFFu + ((u >> 16) & 1u);   // round-nearest-even
  return (unsigned short)(u >> 16);
}
__device__ __forceinline__ float bf2f(unsigned short b) {
  return __uint_as_float(((unsigned int)b) << 16);
}

// ---------------- K1: bf16 convert + sumsq + proj, written CLASS-SORTED ----
// (R7 version — best measured.) 256 blocks x 256 thr; 16 rows/block.
__global__ void __launch_bounds__(256)
k_rows(const float* __restrict__ pred, const float* __restrict__ W,
       const int* __restrict__ tgt, char* __restrict__ ws) {
  __shared__ float Wl[NCLS * DDIM];
  __shared__ float invwn_s[NCLS];
  __shared__ int lcnt[NCLS];
  __shared__ int gbase_s[NCLS];
  __shared__ int slot_s[16];
  int t = threadIdx.x;
  if (t < NCLS) lcnt[t] = 0;
  for (int s = t; s < NCLS * DDIM; s += 256) Wl[s] = W[s];
  __syncthreads();

  int myc = 0, lslot = 0;
  if (t < 16) {
    myc = tgt[blockIdx.x * 16 + t];
    lslot = atomicAdd(&lcnt[myc], 1);
  }
  __syncthreads();
  if (t < NCLS) {
    int n = lcnt[t];
    gbase_s[t] = (n > 0) ? atomicAdd((int*)(ws + WS_GCUR + t * 64), n) : 0;
  }
  if (t >= 64 && t < 224) {            // invwn: 16 lanes/class, into LDS
    int i = t - 64;
    int c = i >> 4, ln = i & 15;
    float sw = 0.f;
#pragma unroll
    for (int k = 0; k < 8; k++) { float w = Wl[c * DDIM + ln * 8 + k]; sw = fmaf(w, w, sw); }
    sw += __shfl_xor(sw, 1, 64);
    sw += __shfl_xor(sw, 2, 64);
    sw += __shfl_xor(sw, 4, 64);
    sw += __shfl_xor(sw, 8, 64);
    if (ln == 0) invwn_s[c] = 1.0f / fmaxf(sqrtf(sw), 1e-8f);
  }
  __syncthreads();
  if (t < 16) slot_s[t] = myc * NROW + gbase_s[myc] + lslot;
  __syncthreads();

  int row  = blockIdx.x * 16 + (t >> 4);
  int part = t & 15;
  int slot = slot_s[t >> 4];
  const float4* p4 = (const float4*)(pred + row * DDIM + part * 8);
  unsigned short* pb = ((unsigned short*)(ws + WS_SPRED)) + slot * DDIM + part * 8;

  float4 v[2];
  float ss = 0.f;
#pragma unroll
  for (int ch = 0; ch < 2; ch++) {
    v[ch] = p4[ch];
    unsigned short b0 = f2bf(v[ch].x), b1 = f2bf(v[ch].y),
                   b2 = f2bf(v[ch].z), b3 = f2bf(v[ch].w);
    float r0 = bf2f(b0), r1 = bf2f(b1), r2 = bf2f(b2), r3 = bf2f(b3);
    ss = fmaf(r0, r0, ss); ss = fmaf(r1, r1, ss);
    ss = fmaf(r2, r2, ss); ss = fmaf(r3, r3, ss);
    ushort4 u; u.x = b0; u.y = b1; u.z = b2; u.w = b3;
    *((ushort4*)(pb + ch * 4)) = u;
  }
  float acc[NCLS];
#pragma unroll
  for (int c = 0; c < NCLS; c++) acc[c] = 0.f;
#pragma unroll
  for (int c = 0; c < NCLS; c++) {
#pragma unroll
    for (int ch = 0; ch < 2; ch++) {
      float4 w = *(const float4*)&Wl[c * DDIM + part * 8 + ch * 4];
      acc[c] = fmaf(v[ch].x, w.x, acc[c]);
      acc[c] = fmaf(v[ch].y, w.y, acc[c]);
      acc[c] = fmaf(v[ch].z, w.z, acc[c]);
      acc[c] = fmaf(v[ch].w, w.w, acc[c]);
    }
  }
#pragma unroll
  for (int m = 1; m <= 8; m <<= 1) {
    ss += __shfl_xor(ss, m, 64);
#pragma unroll
    for (int c = 0; c < NCLS; c++) acc[c] += __shfl_xor(acc[c], m, 64);
  }
  if (part == 0) {
    ((float*)(ws + WS_SSQ))[slot] = ss;
    float* projT = (float*)(ws + WS_PROJT);
#pragma unroll
    for (int c = 0; c < NCLS; c++) projT[c * SLOTS + slot] = acc[c] * invwn_s[c];
  }
}

// ---------------- K2: 256x256 tile-pair MFMA + fused epilogue ----------
// grid 26*26, 512 thr (8 waves), 1 block/CU (133 KB LDS). Both tiles staged
// in LDS via contiguous global_load_lds (XOR chunk swizzle). Wave (wr,wc)
// computes 64 A-rows x 128 B-rows; afrag[4][4] in regs. No global atomics.
__global__ void __launch_bounds__(512, 2)
k_main(char* __restrict__ ws) {
  const int t = threadIdx.x;
  int h[NCLS];
#pragma unroll
  for (int c = 0; c < NCLS; c++) h[c] = *((const int*)(ws + WS_GCUR + c * 64));

  int at = blockIdx.x / MAXT2, bt = blockIdx.x % MAXT2;
  int acc = 0, clsA = 0, ka = 0, clsB = 0, kb = 0;
#pragma unroll
  for (int c = 0; c < NCLS; c++) {
    int tc = (h[c] + TSZ - 1) >> 8;
    if (at >= acc && at < acc + tc) { clsA = c; ka = at - acc; }
    if (bt >= acc && bt < acc + tc) { clsB = c; kb = bt - acc; }
    acc += tc;
  }
  const int ntiles = acc;
  const bool active = (at < ntiles) && (bt < ntiles) && (clsA != clsB);

  __shared__ __align__(16) char Atile[TSZ * 256];   // 64 KB
  __shared__ __align__(16) char Btile[TSZ * 256];   // 64 KB
  __shared__ __align__(16) float sqa_s[TSZ], pa_s[TSZ];
  __shared__ float sqb_s[TSZ], pnb_s[TSZ];
  __shared__ float red_s[8][2];
  float p1 = 0.f, p2 = 0.f;

  if (active) {
    const int abase = clsA * NROW + ka * TSZ;
    const int bbase = clsB * NROW + kb * TSZ;
    const int avcnt = min(TSZ, h[clsA] - ka * TSZ);
    const int bvcnt = min(TSZ, h[clsB] - kb * TSZ);
    const float wg = (1.0f / (float)h[clsA]) * (1.0f / (float)h[clsB]);
    const float INF = __builtin_inff();

    const float* ssq  = (const float*)(ws + WS_SSQ);
    const float* prjA = (const float*)(ws + WS_PROJT) + clsA * SLOTS;
    const unsigned short* spred = (const unsigned short*)(ws + WS_SPRED);

    // ---- scalar staging (pads: sq=INF -> M=0; garbage prj is finite) ----
    {
      int i = t & 255;
      if (t < 256) {
        sqa_s[i] = (i < avcnt) ? ssq[abase + i] : INF;
        pa_s[i]  = prjA[abase + i];
      } else {
        sqb_s[i] = (i < bvcnt) ? ssq[bbase + i] + 1e-16f : INF;
        pnb_s[i] = (i < bvcnt) ? prjA[bbase + i] : 0.0f;
      }
    }

    // ---- tile staging: contiguous rows, 16B/lane, XOR chunk swizzle ----
#pragma unroll
    for (int it = 0; it < 8; it++) {     // A: 256 rows * 16 chunks = 4096
      int s = it * 512 + t;
      int r = s >> 4, cg = (s & 15) ^ (r & 15);
      const unsigned short* gp = spred + (size_t)(abase + r) * DDIM + cg * 8;
      __builtin_amdgcn_global_load_lds(AS1(gp), AS3(Atile + s * 16), 16, 0, 0);
    }
#pragma unroll
    for (int it = 0; it < 8; it++) {     // B: 256 rows * 16 chunks = 4096
      int s = it * 512 + t;
      int r = s >> 4, cg = (s & 15) ^ (r & 15);
      const unsigned short* gp = spred + (size_t)(bbase + r) * DDIM + cg * 8;
      __builtin_amdgcn_global_load_lds(AS1(gp), AS3(Btile + s * 16), 16, 0, 0);
    }
    __syncthreads();                     // drains loads; tiles + scalars ready

    const int lane = t & 63, w = t >> 6;
    const int wr = w >> 1, wc = w & 1;
    const int l16 = lane & 15, quad = lane >> 4;

    // ---- A fragments for this wave's 64 rows ----
    short8 afrag[4][4];
    f32x4 sqa4[4], pa4[4];
#pragma unroll
    for (int fi = 0; fi < 4; fi++) {
      int ra = wr * 64 + fi * 16 + l16;
#pragma unroll
      for (int kk = 0; kk < 4; kk++)
        afrag[fi][kk] = *(const short8*)(Atile + ra * 256 + (((quad + 4 * kk) ^ l16) * 16));
      int m0 = wr * 64 + fi * 16 + quad * 4;      // C-layout row = quad*4+r
      sqa4[fi] = *(const f32x4*)(sqa_s + m0);
      pa4[fi]  = *(const f32x4*)(pa_s + m0);
    }

    float S1 = 0.f, S2 = 0.f;
#pragma unroll
    for (int s = 0; s < 8; s++) {
      int rb = wc * 128 + s * 16 + l16;
      short8 bfrag[4];
#pragma unroll
      for (int kk = 0; kk < 4; kk++)
        bfrag[kk] = *(const short8*)(Btile + rb * 256 + (((quad + 4 * kk) ^ l16) * 16));
      float sqb = sqb_s[rb], pnb = pnb_s[rb];
#pragma unroll
      for (int fi = 0; fi < 4; fi++) {
        f32x4 g = {0.f, 0.f, 0.f, 0.f};
#pragma unroll
        for (int kk = 0; kk < 4; kk++)
          g = __builtin_amdgcn_mfma_f32_16x16x32_bf16(afrag[fi][kk], bfrag[kk], g, 0, 0, 0);
#pragma unroll
        for (int r = 0; r < 4; r++) {
          float d2 = fmaf(-2.0f, g[r], sqa4[fi][r] + sqb);   // pads: inf -> rin 0
          float rin = rsqrtf(d2);                            // 1/dn (maxes are no-ops)
          float M = (pa4[fi][r] - pnb) * rin;
          S1 += M;
          S2 = fmaf(M, M, S2);
        }
      }
    }

#pragma unroll
    for (int off = 32; off > 0; off >>= 1) {
      S1 += __shfl_xor(S1, off, 64);
      S2 += __shfl_xor(S2, off, 64);
    }
    if (lane == 0) { red_s[w][0] = S1; red_s[w][1] = S2; }
    __syncthreads();
    if (t == 0) {
      float a1 = 0.f, a2 = 0.f;
#pragma unroll
      for (int i = 0; i < 8; i++) { a1 += red_s[i][0]; a2 += red_s[i][1]; }
      p1 = wg * a1; p2 = wg * a2;
    }
  }

  if (t == 0) {                          // unique-slot partial (plain store)
    float* part = (float*)(ws + WS_PART);
    part[blockIdx.x * 2]     = p1;
    part[blockIdx.x * 2 + 1] = p2;
  }
}

// ---------------- K3: reduce partials per class, emit outputs ----------
__global__ void __launch_bounds__(256)
k_final(const char* __restrict__ ws, float* __restrict__ out) {
  __shared__ float Sred[2 * NCLS];
  __shared__ int tcls_s[MAXT2];
  __shared__ int h_s[NCLS];
  int t = threadIdx.x;
  if (t < 2 * NCLS) Sred[t] = 0.f;
  if (t < NCLS) h_s[t] = *((const int*)(ws + WS_GCUR + t * 64));
  __syncthreads();
  if (t == 0) {
    int nb = 0;
    for (int c = 0; c < NCLS; c++) {
      int tc = (h_s[c] + TSZ - 1) >> 8;
      for (int i = 0; i < tc && nb + i < MAXT2; i++) tcls_s[nb + i] = c;
      nb += tc;
    }
    for (int i = nb; i < MAXT2; i++) tcls_s[i] = 0;  // inactive rows wrote zeros
  }
  __syncthreads();
  const float* part = (const float*)(ws + WS_PART);
  for (int i = t; i < GRID2; i += 256) {
    int c = tcls_s[i / MAXT2];
    float v1 = part[i * 2], v2 = part[i * 2 + 1];
    if (v1 != 0.f || v2 != 0.f) {
      atomicAdd(&Sred[c], v1);
      atomicAdd(&Sred[NCLS + c], v2);
    }
  }
  __syncthreads();
  if (t == 0) {
    float exist = 0.f;
    for (int c = 0; c < NCLS; c++) if (h_s[c] > 0) exist += 1.f;
    float em1 = exist - 1.0f;          // S0 per class == exist-1 (exact)
    float l1 = 0.f, l2 = 0.f;
    for (int c = 0; c < NCLS; c++) {
      if (h_s[c] <= 0) continue;
      float s1 = Sred[c], s2 = Sred[NCLS + c];
      l1 += (em1 - 2.f * s1 + s2) / em1;
      float mm = s1 / em1;
      float mv = s2 / em1 - mm * mm;   // (S2 - 2*mm*S1 + mm^2*S0)/em1, S0=em1
      l2 += fabsf(mv / mm);
    }
    out[0] = l1 / exist;
    out[1] = l2 / exist;
  }
}

extern "C" void kernel_launch(void* const* d_in, const int* in_sizes, int n_in,
                              void* d_out, int out_size, void* d_ws, size_t ws_size,
                              hipStream_t stream) {
  const float* pred = (const float*)d_in[0];
  const int*   tgt  = (const int*)d_in[1];
  const float* W    = (const float*)d_in[2];
  float* out = (float*)d_out;
  char*  ws  = (char*)d_ws;

  hipMemsetAsync(ws, 0, 1024, stream);   // zero GCUR
  k_rows<<<NROW / 16, 256, 0, stream>>>(pred, W, tgt, ws);
  k_main<<<GRID2, 512, 0, stream>>>(ws);
  k_final<<<1, 256, 0, stream>>>(ws, out);
}